// Round 8
// baseline (135.710 us; speedup 1.0000x reference)
//
#include <hip/hip_runtime.h>
#include <hip/hip_bf16.h>

#define BB 8
#define NN 2048
#define EE 64
#define DD 128
#define BN (BB * NN)

typedef __attribute__((ext_vector_type(8))) short short8v;
typedef __attribute__((ext_vector_type(4))) float float4v;

__device__ __forceinline__ short f2bf(float f) {
    __hip_bfloat16 h = __float2bfloat16(f);
    return *reinterpret_cast<short*>(&h);
}
__device__ __forceinline__ uint32_t pack2bf(float a, float b) {
    return (uint32_t)(uint16_t)f2bf(a) | ((uint32_t)(uint16_t)f2bf(b) << 16);
}

#define GLD16(gp, lp)                                                          \
    __builtin_amdgcn_global_load_lds(                                          \
        (const __attribute__((address_space(1))) void*)(gp),                   \
        (__attribute__((address_space(3))) void*)(lp), 16, 0, 0)
#define GLD4(gp, lp)                                                           \
    __builtin_amdgcn_global_load_lds(                                          \
        (const __attribute__((address_space(1))) void*)(gp),                   \
        (__attribute__((address_space(3))) void*)(lp), 4, 0, 0)

// ---------------- fused prep: embq | zq | sq + counter zeroing ----------------
__global__ __launch_bounds__(256) void prep_kernel(const float* __restrict__ emb,
                                                   const float* __restrict__ z,
                                                   short* __restrict__ embq,
                                                   short* __restrict__ zq,
                                                   float* __restrict__ sq,
                                                   int* __restrict__ cnt) {
    __shared__ float zl[64 * 129];
    const int bid = blockIdx.x;
    const int t = threadIdx.x;

    if (bid < 512) {
        int gid = bid * 256 + t;
        int s = gid & 63;
        int ke = (gid >> 6) & 1;
        int r16 = (gid >> 7) & 127;
        int b = gid >> 14;
        int i = r16 * 16 + (s & 15);
        int e0 = ke * 32 + ((s >> 4) & 3) * 8;
        const float4* src = reinterpret_cast<const float4*>(emb + ((size_t)(b * NN + i)) * EE + e0);
        float4 v0 = src[0], v1 = src[1];
        short8v o;
        o[0] = f2bf(v0.x); o[1] = f2bf(v0.y); o[2] = f2bf(v0.z); o[3] = f2bf(v0.w);
        o[4] = f2bf(v1.x); o[5] = f2bf(v1.y); o[6] = f2bf(v1.z); o[7] = f2bf(v1.w);
        *reinterpret_cast<short8v*>(embq + (size_t)gid * 8) = o;
    } else if (bid < 768) {
        int v = bid - 512;  // b*32 + jt
        int b = v >> 5;
        int jt = v & 31;
        int jb = jt * 64;
#pragma unroll
        for (int k = 0; k < 8; ++k) {
            int idx = t + k * 256;
            int jl = idx >> 5, c4 = idx & 31;
            float4 w = reinterpret_cast<const float4*>(z + ((size_t)(b * NN + jb + jl)) * DD)[c4];
            float* p = &zl[jl * 129 + c4 * 4];
            p[0] = w.x; p[1] = w.y; p[2] = w.z; p[3] = w.w;
        }
        __syncthreads();
#pragma unroll
        for (int k = 0; k < 4; ++k) {
            int sid = t + k * 256;
            int blk = sid >> 6, s = sid & 63;
            int ktl = blk >> 3, nt = blk & 7;
            int d = nt * 16 + (s & 15);
            int jl = ktl * 32 + ((s >> 4) & 3) * 8;
            short8v o;
#pragma unroll
            for (int e = 0; e < 8; ++e) o[e] = f2bf(zl[(jl + e) * 129 + d]);
            *reinterpret_cast<short8v*>(zq + ((size_t)((b * 64 + jt * 2 + ktl) * 8 + nt) * 64 + s) * 8) = o;
        }
    } else {
        int v = bid - 768;
        if (v == 0) cnt[t] = 0;  // zero the 256 group counters every launch
        int q = t & 15;
#pragma unroll
        for (int p = 0; p < 4; ++p) {
            int row = v * 64 + p * 16 + (t >> 4);
            float4 rv = reinterpret_cast<const float4*>(emb + (size_t)row * EE)[q];
            float a0 = __bfloat162float(__float2bfloat16(rv.x));
            float a1 = __bfloat162float(__float2bfloat16(rv.y));
            float a2 = __bfloat162float(__float2bfloat16(rv.z));
            float a3 = __bfloat162float(__float2bfloat16(rv.w));
            float s2 = a0 * a0 + a1 * a1 + a2 * a2 + a3 * a3;
#pragma unroll
            for (int off = 1; off < 16; off <<= 1) s2 += __shfl_xor(s2, off);
            if (q == 0) sq[row] = s2;
        }
    }
}

// ---------------- main MFMA attention + decoupled last-block reduce ----------------
// grid: bid = ((js*32 + it))*8 + b (XCD-pinned batch). 4 waves; wave owns 16 rows.
// QK (swapped): lane (g,c) holds S[i=w*16+c][j=J*16+4g+r]. Vote-before-exp skips
// negligible work (all p < 1e-6 => bounded truncation, out err < ~0.011 worst case).
// njs>1: partials to num/den; per row-group counter; LAST arriving block reduces.
__global__ __launch_bounds__(256, 4) void attn_mfma(const short* __restrict__ embq,
                                                    const short* __restrict__ zq,
                                                    const float* __restrict__ sq,
                                                    float* __restrict__ outC,
                                                    float* __restrict__ num,
                                                    float* __restrict__ den,
                                                    int* __restrict__ cnt,
                                                    int njs) {
    __shared__ short sU[4][1024];   // 8KB union: embI staging (prologue) -> per-wave P^T
    __shared__ int4 sEmbJ[2][512];  // 16KB dbuf [jfr(4)][ke(2)][64]
    __shared__ float sSqJ[2][64];
    __shared__ float sDenA[4][64];  // last-block reduce: den slices
    __shared__ int sLast;

    const int t = threadIdx.x;
    const int bid = blockIdx.x;
    const int b = bid & 7;
    const int q = bid >> 3;
    const int it = q & 31;
    const int js = q >> 5;
    const int ib = it * 64;
    const int w = t >> 6;
    const int l = t & 63;
    const int g = (l >> 4) & 3;
    const int c = l & 15;

    const int4* embqI4 = (const int4*)embq;
    const short8v* zq8 = (const short8v*)zq;
    const float* sqB = sq + b * NN;

    const int ntiles = 32 / njs;
    const int jt0 = js * ntiles;
    const int jtEnd = jt0 + ntiles;

    int4* sUi = (int4*)&sU[0][0];

    // prologue: stage embI (64 rows) into union + tile0 embJ + sq; drain once
    {
        const int4* srcI = embqI4 + (size_t)(b * 128 + it * 4) * 2 * 64;
        GLD16(srcI + t, sUi + t);
        GLD16(srcI + t + 256, sUi + t + 256);
        const int4* srcJ = embqI4 + (size_t)(b * 128 + jt0 * 4) * 2 * 64;
        GLD16(srcJ + t, &sEmbJ[0][t]);
        GLD16(srcJ + t + 256, &sEmbJ[0][t + 256]);
        if (t < 64) GLD4(sqB + jt0 * 64 + t, &sSqJ[0][t]);
    }
    __syncthreads();

    // wave w reads exactly its own sU[w] 2KB region, later reused as its P^T scratch
    short8v qkB[2];
    qkB[0] = *reinterpret_cast<const short8v*>(&sUi[(w * 2 + 0) * 64 + l]);
    qkB[1] = *reinterpret_cast<const short8v*>(&sUi[(w * 2 + 1) * 64 + l]);
    const float sqi = sqB[ib + w * 16 + c];

    float dsum = 0.f;
    float4v acc[8];
#pragma unroll
    for (int nt = 0; nt < 8; ++nt) acc[nt] = (float4v){0.f, 0.f, 0.f, 0.f};

    char* ptw = (char*)&sU[w][0];
    const int swz = (c & 7) << 4;

    int cur = 0;
    for (int jt = jt0; jt < jtEnd; ++jt, cur ^= 1) {
        {   // prefetch next embJ + sq (drained by end-of-tile barrier)
            int jn = (jt + 1 < jtEnd) ? jt + 1 : jt;
            int nxt = cur ^ 1;
            const int4* srcJ = embqI4 + (size_t)(b * 128 + jn * 4) * 2 * 64;
            GLD16(srcJ + t, &sEmbJ[nxt][t]);
            GLD16(srcJ + t + 256, &sEmbJ[nxt][t + 256]);
            if (t < 64) GLD4(sqB + jn * 64 + t, &sSqJ[nxt][t]);
        }

        // ---- QK (swapped) + d2 only; no exp yet ----
        float d2v[4][4];
        float d2minJ[4];
#pragma unroll
        for (int J = 0; J < 4; ++J) {
            short8v a0 = *reinterpret_cast<const short8v*>(&sEmbJ[cur][(J * 2 + 0) * 64 + l]);
            short8v a1 = *reinterpret_cast<const short8v*>(&sEmbJ[cur][(J * 2 + 1) * 64 + l]);
            float4v sfr = (float4v){0.f, 0.f, 0.f, 0.f};
            sfr = __builtin_amdgcn_mfma_f32_16x16x32_bf16(a0, qkB[0], sfr, 0, 0, 0);
            sfr = __builtin_amdgcn_mfma_f32_16x16x32_bf16(a1, qkB[1], sfr, 0, 0, 0);
            float4 sqj = *reinterpret_cast<const float4*>(&sSqJ[cur][J * 16 + 4 * g]);
            d2v[J][0] = fmaxf(fmaf(-2.0f, sfr[0], sqi + sqj.x), 0.0f);
            d2v[J][1] = fmaxf(fmaf(-2.0f, sfr[1], sqi + sqj.y), 0.0f);
            d2v[J][2] = fmaxf(fmaf(-2.0f, sfr[2], sqi + sqj.z), 0.0f);
            d2v[J][3] = fmaxf(fmaf(-2.0f, sfr[3], sqi + sqj.w), 0.0f);
            d2minJ[J] = fminf(fminf(d2v[J][0], d2v[J][1]), fminf(d2v[J][2], d2v[J][3]));
        }
        float tmin = fminf(fminf(d2minJ[0], d2minJ[1]), fminf(d2minJ[2], d2minJ[3]));

        // ---- exp/pack/PV only when some p >= 1e-6 anywhere in the wave-tile ----
        if (!__all(tmin > 13.8f)) {
#pragma unroll
            for (int J = 0; J < 4; ++J) {
                unsigned long long pword = 0ull;
                if (!__all(d2minJ[J] > 13.8f)) {
                    float p0 = __expf(-d2v[J][0]);
                    float p1 = __expf(-d2v[J][1]);
                    float p2 = __expf(-d2v[J][2]);
                    float p3 = __expf(-d2v[J][3]);
                    dsum += (p0 + p1) + (p2 + p3);
                    pword = (unsigned long long)pack2bf(p0, p1) |
                            ((unsigned long long)pack2bf(p2, p3) << 32);
                }
                *reinterpret_cast<unsigned long long*>(
                    ptw + ((c * 128 + g * 8) ^ swz ^ (J * 32))) = pword;
            }
            short8v pa0 = *reinterpret_cast<const short8v*>(ptw + ((c * 128 + 0 * 64 + g * 16) ^ swz));
            short8v pa1 = *reinterpret_cast<const short8v*>(ptw + ((c * 128 + 1 * 64 + g * 16) ^ swz));
#pragma unroll
            for (int nt = 0; nt < 8; ++nt) {
                short8v z0 = zq8[(size_t)((b * 64 + jt * 2 + 0) * 8 + nt) * 64 + l];
                short8v z1 = zq8[(size_t)((b * 64 + jt * 2 + 1) * 8 + nt) * 64 + l];
                acc[nt] = __builtin_amdgcn_mfma_f32_16x16x32_bf16(pa0, z0, acc[nt], 0, 0, 0);
                acc[nt] = __builtin_amdgcn_mfma_f32_16x16x32_bf16(pa1, z1, acc[nt], 0, 0, 0);
            }
        }

        __syncthreads();  // single sync: guards sEmbJ dbuf reuse + drains prefetch
    }

    // dsum reduce over g-groups -> all lanes hold row-c sum
    dsum += __shfl_xor(dsum, 16);
    dsum += __shfl_xor(dsum, 32);

    if (njs == 1) {
        float invr[4];
#pragma unroll
        for (int r = 0; r < 4; ++r) invr[r] = 1.0f / __shfl(dsum, 4 * g + r);
#pragma unroll
        for (int r = 0; r < 4; ++r) {
            size_t row = (size_t)(b * NN + ib + w * 16 + 4 * g + r);
#pragma unroll
            for (int nt = 0; nt < 8; ++nt)
                outC[row * DD + nt * 16 + c] = acc[nt][r] * invr[r];
        }
        return;
    }

    // ---- partials ----
    if (l < 16) den[(size_t)js * BN + b * NN + ib + w * 16 + l] = dsum;
    if (!__all(dsum < 1e-6f)) {  // whole-wave-slice negligible -> skip (gated by den on read)
#pragma unroll
        for (int r = 0; r < 4; ++r) {
            size_t row = (size_t)js * BN + b * NN + ib + w * 16 + 4 * g + r;
#pragma unroll
            for (int nt = 0; nt < 8; ++nt)
                num[row * DD + nt * 16 + c] = acc[nt][r];
        }
    }

    // ---- decoupled completion: last arriving block of this row-group reduces ----
    __threadfence();   // release: make num/den visible device-wide
    __syncthreads();   // all waves' stores+fences before the atomic
    if (t == 0) {
        int old = atomicAdd(&cnt[it * 8 + b], 1);
        sLast = (old == njs - 1) ? 1 : 0;
    }
    __syncthreads();
    if (sLast) {
        __threadfence();  // acquire: see other blocks' num/den
        if (t < 64) {
            for (int s2 = 0; s2 < njs; ++s2)
                sDenA[s2][t] = den[(size_t)s2 * BN + b * NN + ib + t];
        }
        __syncthreads();
        // 64 rows x 128 cols fp32 = 2048 float4; thread handles 8 lane-consecutive sweeps
#pragma unroll
        for (int k = 0; k < 8; ++k) {
            int i4 = t + k * 256;
            int row = i4 >> 5, c4 = i4 & 31;
            float ds = 0.f;
            float4 ns = make_float4(0.f, 0.f, 0.f, 0.f);
            for (int s2 = 0; s2 < njs; ++s2) {
                float dj = sDenA[s2][row];
                ds += dj;
                if (dj >= 1e-6f) {
                    float4 v = reinterpret_cast<const float4*>(
                        num + ((size_t)s2 * BN + b * NN + ib + row) * DD)[c4];
                    ns.x += v.x; ns.y += v.y; ns.z += v.z; ns.w += v.w;
                }
            }
            float inv = 1.0f / ds;
            reinterpret_cast<float4*>(outC + (size_t)(b * NN + ib + row) * DD)[c4] =
                make_float4(ns.x * inv, ns.y * inv, ns.z * inv, ns.w * inv);
        }
    }
}

extern "C" void kernel_launch(void* const* d_in, const int* in_sizes, int n_in,
                              void* d_out, int out_size, void* d_ws, size_t ws_size,
                              hipStream_t stream) {
    (void)in_sizes; (void)n_in; (void)out_size;
    const float* emb = (const float*)d_in[0];
    const float* z = (const float*)d_in[1];
    float* out = (float*)d_out;
    float* ws = (float*)d_ws;

    // ws layout (floats): sq[BN] | den[njs*BN] | num[njs*BN*DD] | cnt[256] | embq(1M sh) | zq(2M sh)
    int njs = 1;
    if (ws_size >= 40ull * 1024 * 1024) njs = 4;
    else if (ws_size >= 24ull * 1024 * 1024) njs = 2;

    float* sqw = ws;
    float* denw = ws + BN;
    float* numw = denw + (size_t)njs * BN;
    size_t numFloats = (njs > 1) ? (size_t)njs * BN * DD : 0;
    int* cntw = (int*)(numw + numFloats);
    short* embqw = (short*)(cntw + 256);
    short* zqw = embqw + (size_t)BB * NN * EE;

    prep_kernel<<<1024, 256, 0, stream>>>(emb, z, embqw, zqw, sqw, cntw);

    attn_mfma<<<8 * 32 * njs, 256, 0, stream>>>(embqw, zqw, sqw, out, numw, denw,
                                                cntw, njs);
}

// Round 9
// 31.688 us; speedup vs baseline: 4.2827x; 4.2827x over previous
//
#include <hip/hip_runtime.h>
#include <hip/hip_bf16.h>

#define BB 8
#define NN 2048
#define EE 64
#define DD 128
#define BN (BB * NN)

typedef __attribute__((ext_vector_type(8))) short short8v;
typedef __attribute__((ext_vector_type(4))) float float4v;

__device__ __forceinline__ short f2bf(float f) {
    __hip_bfloat16 h = __float2bfloat16(f);
    return *reinterpret_cast<short*>(&h);
}
__device__ __forceinline__ uint32_t pack2bf(float a, float b) {
    return (uint32_t)(uint16_t)f2bf(a) | ((uint32_t)(uint16_t)f2bf(b) << 16);
}

#define GLD16(gp, lp)                                                          \
    __builtin_amdgcn_global_load_lds(                                          \
        (const __attribute__((address_space(1))) void*)(gp),                   \
        (__attribute__((address_space(3))) void*)(lp), 16, 0, 0)
#define GLD4(gp, lp)                                                           \
    __builtin_amdgcn_global_load_lds(                                          \
        (const __attribute__((address_space(1))) void*)(gp),                   \
        (__attribute__((address_space(3))) void*)(lp), 4, 0, 0)

// ---------------- fused prep: embq | zq | sq ----------------
// blocks [0,512): embq  — slot ((b*128+r16)*2+ke)*64+s holds emb[b][r16*16+(s&15)][ke*32+((s>>4)&3)*8+e]
// blocks [512,768): zq  — slot ((b*64+jkt)*8+nt)*64+s holds z[b][jkt*32+((s>>4)&3)*8+e][nt*16+(s&15)]
// blocks [768,1024): sq — sq[row] = ||bf16(emb[row,:])||^2
__global__ __launch_bounds__(256) void prep_kernel(const float* __restrict__ emb,
                                                   const float* __restrict__ z,
                                                   short* __restrict__ embq,
                                                   short* __restrict__ zq,
                                                   float* __restrict__ sq) {
    __shared__ float zl[64 * 129];
    const int bid = blockIdx.x;
    const int t = threadIdx.x;

    if (bid < 512) {
        int gid = bid * 256 + t;
        int s = gid & 63;
        int ke = (gid >> 6) & 1;
        int r16 = (gid >> 7) & 127;
        int b = gid >> 14;
        int i = r16 * 16 + (s & 15);
        int e0 = ke * 32 + ((s >> 4) & 3) * 8;
        const float4* src = reinterpret_cast<const float4*>(emb + ((size_t)(b * NN + i)) * EE + e0);
        float4 v0 = src[0], v1 = src[1];
        short8v o;
        o[0] = f2bf(v0.x); o[1] = f2bf(v0.y); o[2] = f2bf(v0.z); o[3] = f2bf(v0.w);
        o[4] = f2bf(v1.x); o[5] = f2bf(v1.y); o[6] = f2bf(v1.z); o[7] = f2bf(v1.w);
        *reinterpret_cast<short8v*>(embq + (size_t)gid * 8) = o;
    } else if (bid < 768) {
        int v = bid - 512;  // b*32 + jt
        int b = v >> 5;
        int jt = v & 31;
        int jb = jt * 64;
#pragma unroll
        for (int k = 0; k < 8; ++k) {
            int idx = t + k * 256;
            int jl = idx >> 5, c4 = idx & 31;
            float4 w = reinterpret_cast<const float4*>(z + ((size_t)(b * NN + jb + jl)) * DD)[c4];
            float* p = &zl[jl * 129 + c4 * 4];
            p[0] = w.x; p[1] = w.y; p[2] = w.z; p[3] = w.w;
        }
        __syncthreads();
#pragma unroll
        for (int k = 0; k < 4; ++k) {
            int sid = t + k * 256;
            int blk = sid >> 6, s = sid & 63;
            int ktl = blk >> 3, nt = blk & 7;
            int d = nt * 16 + (s & 15);
            int jl = ktl * 32 + ((s >> 4) & 3) * 8;
            short8v o;
#pragma unroll
            for (int e = 0; e < 8; ++e) o[e] = f2bf(zl[(jl + e) * 129 + d]);
            *reinterpret_cast<short8v*>(zq + ((size_t)((b * 64 + jt * 2 + ktl) * 8 + nt) * 64 + s) * 8) = o;
        }
    } else {
        int v = bid - 768;
        int q = t & 15;
#pragma unroll
        for (int p = 0; p < 4; ++p) {
            int row = v * 64 + p * 16 + (t >> 4);
            float4 rv = reinterpret_cast<const float4*>(emb + (size_t)row * EE)[q];
            float a0 = __bfloat162float(__float2bfloat16(rv.x));
            float a1 = __bfloat162float(__float2bfloat16(rv.y));
            float a2 = __bfloat162float(__float2bfloat16(rv.z));
            float a3 = __bfloat162float(__float2bfloat16(rv.w));
            float s2 = a0 * a0 + a1 * a1 + a2 * a2 + a3 * a3;
#pragma unroll
            for (int off = 1; off < 16; off <<= 1) s2 += __shfl_xor(s2, off);
            if (q == 0) sq[row] = s2;
        }
    }
}

// ---------------- main MFMA attention ----------------
// grid: bid = ((js*32 + it))*8 + b (XCD-pinned batch). 4 waves; wave owns 16 rows.
// QK (swapped): lane (g,c) holds S[i=w*16+c][j=J*16+4g+r] for J=0..3.
// Vote-before-exp: per-J wave vote (all d2 > 13.8 => all p < 1e-6) skips exp/pack;
// whole-tile vote skips PV. Bounded truncation: out err < ~0.011 worst case.
// P via same-wave XOR-swizzled LDS transpose in a wave-private 2KB union region.
// launch_bounds(256,6): 6 blocks/CU (LDS 25KB*6=150KB, VGPR ~56) -> 24 waves/CU.
__global__ __launch_bounds__(256, 6) void attn_mfma(const short* __restrict__ embq,
                                                    const short* __restrict__ zq,
                                                    const float* __restrict__ sq,
                                                    float* __restrict__ outnum,
                                                    float* __restrict__ den,
                                                    int njs) {
    __shared__ short sU[4][1024];   // 8KB union: embI staging (prologue) -> per-wave P^T
    __shared__ int4 sEmbJ[2][512];  // 16KB dbuf [jfr(4)][ke(2)][64]
    __shared__ float sSqJ[2][64];

    const int t = threadIdx.x;
    const int bid = blockIdx.x;
    const int b = bid & 7;
    const int q = bid >> 3;
    const int it = q & 31;
    const int js = q >> 5;
    const int ib = it * 64;
    const int w = t >> 6;
    const int l = t & 63;
    const int g = (l >> 4) & 3;
    const int c = l & 15;

    const int4* embqI4 = (const int4*)embq;
    const short8v* zq8 = (const short8v*)zq;
    const float* sqB = sq + b * NN;

    const int ntiles = 32 / njs;
    const int jt0 = js * ntiles;
    const int jtEnd = jt0 + ntiles;

    int4* sUi = (int4*)&sU[0][0];

    // prologue: stage embI (64 rows) into union + tile0 embJ + sq; drain once
    {
        const int4* srcI = embqI4 + (size_t)(b * 128 + it * 4) * 2 * 64;
        GLD16(srcI + t, sUi + t);
        GLD16(srcI + t + 256, sUi + t + 256);
        const int4* srcJ = embqI4 + (size_t)(b * 128 + jt0 * 4) * 2 * 64;
        GLD16(srcJ + t, &sEmbJ[0][t]);
        GLD16(srcJ + t + 256, &sEmbJ[0][t + 256]);
        if (t < 64) GLD4(sqB + jt0 * 64 + t, &sSqJ[0][t]);
    }
    __syncthreads();

    // wave w reads exactly its own sU[w] 2KB region, later reused as its P^T scratch
    short8v qkB[2];
    qkB[0] = *reinterpret_cast<const short8v*>(&sUi[(w * 2 + 0) * 64 + l]);
    qkB[1] = *reinterpret_cast<const short8v*>(&sUi[(w * 2 + 1) * 64 + l]);
    const float sqi = sqB[ib + w * 16 + c];

    float dsum = 0.f;
    float4v acc[8];
#pragma unroll
    for (int nt = 0; nt < 8; ++nt) acc[nt] = (float4v){0.f, 0.f, 0.f, 0.f};

    char* ptw = (char*)&sU[w][0];
    const int swz = (c & 7) << 4;

    int cur = 0;
    for (int jt = jt0; jt < jtEnd; ++jt, cur ^= 1) {
        {   // prefetch next embJ + sq (drained by end-of-tile barrier)
            int jn = (jt + 1 < jtEnd) ? jt + 1 : jt;
            int nxt = cur ^ 1;
            const int4* srcJ = embqI4 + (size_t)(b * 128 + jn * 4) * 2 * 64;
            GLD16(srcJ + t, &sEmbJ[nxt][t]);
            GLD16(srcJ + t + 256, &sEmbJ[nxt][t + 256]);
            if (t < 64) GLD4(sqB + jn * 64 + t, &sSqJ[nxt][t]);
        }

        // ---- QK (swapped) + d2 only; no exp yet ----
        float d2v[4][4];
        float d2minJ[4];
#pragma unroll
        for (int J = 0; J < 4; ++J) {
            short8v a0 = *reinterpret_cast<const short8v*>(&sEmbJ[cur][(J * 2 + 0) * 64 + l]);
            short8v a1 = *reinterpret_cast<const short8v*>(&sEmbJ[cur][(J * 2 + 1) * 64 + l]);
            float4v sfr = (float4v){0.f, 0.f, 0.f, 0.f};
            sfr = __builtin_amdgcn_mfma_f32_16x16x32_bf16(a0, qkB[0], sfr, 0, 0, 0);
            sfr = __builtin_amdgcn_mfma_f32_16x16x32_bf16(a1, qkB[1], sfr, 0, 0, 0);
            float4 sqj = *reinterpret_cast<const float4*>(&sSqJ[cur][J * 16 + 4 * g]);
            d2v[J][0] = fmaxf(fmaf(-2.0f, sfr[0], sqi + sqj.x), 0.0f);
            d2v[J][1] = fmaxf(fmaf(-2.0f, sfr[1], sqi + sqj.y), 0.0f);
            d2v[J][2] = fmaxf(fmaf(-2.0f, sfr[2], sqi + sqj.z), 0.0f);
            d2v[J][3] = fmaxf(fmaf(-2.0f, sfr[3], sqi + sqj.w), 0.0f);
            d2minJ[J] = fminf(fminf(d2v[J][0], d2v[J][1]), fminf(d2v[J][2], d2v[J][3]));
        }
        float tmin = fminf(fminf(d2minJ[0], d2minJ[1]), fminf(d2minJ[2], d2minJ[3]));

        // ---- exp/pack/PV only when some p >= 1e-6 anywhere in the wave-tile ----
        if (!__all(tmin > 13.8f)) {
#pragma unroll
            for (int J = 0; J < 4; ++J) {
                unsigned long long pword = 0ull;
                if (!__all(d2minJ[J] > 13.8f)) {
                    float p0 = __expf(-d2v[J][0]);
                    float p1 = __expf(-d2v[J][1]);
                    float p2 = __expf(-d2v[J][2]);
                    float p3 = __expf(-d2v[J][3]);
                    dsum += (p0 + p1) + (p2 + p3);
                    pword = (unsigned long long)pack2bf(p0, p1) |
                            ((unsigned long long)pack2bf(p2, p3) << 32);
                }
                *reinterpret_cast<unsigned long long*>(
                    ptw + ((c * 128 + g * 8) ^ swz ^ (J * 32))) = pword;
            }
            short8v pa0 = *reinterpret_cast<const short8v*>(ptw + ((c * 128 + 0 * 64 + g * 16) ^ swz));
            short8v pa1 = *reinterpret_cast<const short8v*>(ptw + ((c * 128 + 1 * 64 + g * 16) ^ swz));
#pragma unroll
            for (int nt = 0; nt < 8; ++nt) {
                short8v z0 = zq8[(size_t)((b * 64 + jt * 2 + 0) * 8 + nt) * 64 + l];
                short8v z1 = zq8[(size_t)((b * 64 + jt * 2 + 1) * 8 + nt) * 64 + l];
                acc[nt] = __builtin_amdgcn_mfma_f32_16x16x32_bf16(pa0, z0, acc[nt], 0, 0, 0);
                acc[nt] = __builtin_amdgcn_mfma_f32_16x16x32_bf16(pa1, z1, acc[nt], 0, 0, 0);
            }
        }

        __syncthreads();  // single sync: guards sEmbJ dbuf reuse + drains prefetch
    }

    // dsum reduce over g-groups -> all lanes hold row-c sum
    dsum += __shfl_xor(dsum, 16);
    dsum += __shfl_xor(dsum, 32);

    if (njs == 1) {
        float invr[4];
#pragma unroll
        for (int r = 0; r < 4; ++r) invr[r] = 1.0f / __shfl(dsum, 4 * g + r);
#pragma unroll
        for (int r = 0; r < 4; ++r) {
            size_t row = (size_t)(b * NN + ib + w * 16 + 4 * g + r);
#pragma unroll
            for (int nt = 0; nt < 8; ++nt)
                outnum[row * DD + nt * 16 + c] = acc[nt][r] * invr[r];
        }
    } else {
        if (l < 16) den[(size_t)js * BN + b * NN + ib + w * 16 + l] = dsum;
        // skip num writes when this wave's whole j-slice carries no mass
        if (!__all(dsum < 1e-6f)) {
#pragma unroll
            for (int r = 0; r < 4; ++r) {
                size_t row = (size_t)js * BN + b * NN + ib + w * 16 + 4 * g + r;
#pragma unroll
                for (int nt = 0; nt < 8; ++nt)
                    outnum[row * DD + nt * 16 + c] = acc[nt][r];
            }
        }
    }
}

// ---------------- reduce: out = sum_js num / sum_js den, num reads gated by den ----------------
__global__ __launch_bounds__(256) void reduce_kernel(const float4* __restrict__ num,
                                                     const float* __restrict__ den,
                                                     float4* __restrict__ out,
                                                     int njs) {
    int i4 = blockIdx.x * 256 + threadIdx.x;
    int row = i4 >> 5;
    float4 ns = make_float4(0.f, 0.f, 0.f, 0.f);
    float ds = 0.f;
    for (int js = 0; js < njs; ++js) {
        float dj = den[(size_t)js * BN + row];
        ds += dj;
        if (dj >= 1e-6f) {  // slices below tau were never written (and contribute < 1e-5)
            float4 v = num[(size_t)js * ((size_t)BN * (DD / 4)) + i4];
            ns.x += v.x; ns.y += v.y; ns.z += v.z; ns.w += v.w;
        }
    }
    float inv = 1.0f / ds;
    out[i4] = make_float4(ns.x * inv, ns.y * inv, ns.z * inv, ns.w * inv);
}

extern "C" void kernel_launch(void* const* d_in, const int* in_sizes, int n_in,
                              void* d_out, int out_size, void* d_ws, size_t ws_size,
                              hipStream_t stream) {
    (void)in_sizes; (void)n_in; (void)out_size;
    const float* emb = (const float*)d_in[0];
    const float* z = (const float*)d_in[1];
    float* out = (float*)d_out;
    float* ws = (float*)d_ws;

    // ws layout (floats): sq[BN] | den[njs*BN] | num[njs*BN*DD] | embq(1M shorts) | zq(2M shorts)
    int njs = 1;
    if (ws_size >= 40ull * 1024 * 1024) njs = 4;
    else if (ws_size >= 24ull * 1024 * 1024) njs = 2;

    float* sqw = ws;
    float* denw = ws + BN;
    float* numw = denw + (size_t)njs * BN;
    size_t numFloats = (njs > 1) ? (size_t)njs * BN * DD : 0;
    short* embqw = (short*)(numw + numFloats);
    short* zqw = embqw + (size_t)BB * NN * EE;

    prep_kernel<<<1024, 256, 0, stream>>>(emb, z, embqw, zqw, sqw);

    attn_mfma<<<8 * 32 * njs, 256, 0, stream>>>(embqw, zqw, sqw,
                                                njs == 1 ? out : numw, denw, njs);

    if (njs > 1) {
        reduce_kernel<<<(BN * (DD / 4)) / 256, 256, 0, stream>>>(
            (const float4*)numw, denw, (float4*)out, njs);
    }
}

// Round 10
// 29.608 us; speedup vs baseline: 4.5835x; 1.0702x over previous
//
#include <hip/hip_runtime.h>
#include <hip/hip_bf16.h>

#define BB 8
#define NN 2048
#define EE 64
#define DD 128
#define BN (BB * NN)

typedef __attribute__((ext_vector_type(8))) short short8v;
typedef __attribute__((ext_vector_type(4))) float float4v;

__device__ __forceinline__ short f2bf(float f) {
    __hip_bfloat16 h = __float2bfloat16(f);
    return *reinterpret_cast<short*>(&h);
}
__device__ __forceinline__ uint32_t pack2bf(float a, float b) {
    return (uint32_t)(uint16_t)f2bf(a) | ((uint32_t)(uint16_t)f2bf(b) << 16);
}

#define GLD16(gp, lp)                                                          \
    __builtin_amdgcn_global_load_lds(                                          \
        (const __attribute__((address_space(1))) void*)(gp),                   \
        (__attribute__((address_space(3))) void*)(lp), 16, 0, 0)
#define GLD4(gp, lp)                                                           \
    __builtin_amdgcn_global_load_lds(                                          \
        (const __attribute__((address_space(1))) void*)(gp),                   \
        (__attribute__((address_space(3))) void*)(lp), 4, 0, 0)

// ---------------- fused prep: embq | zq | sq ----------------
__global__ __launch_bounds__(256) void prep_kernel(const float* __restrict__ emb,
                                                   const float* __restrict__ z,
                                                   short* __restrict__ embq,
                                                   short* __restrict__ zq,
                                                   float* __restrict__ sq) {
    __shared__ float zl[64 * 129];
    const int bid = blockIdx.x;
    const int t = threadIdx.x;

    if (bid < 512) {
        int gid = bid * 256 + t;
        int s = gid & 63;
        int ke = (gid >> 6) & 1;
        int r16 = (gid >> 7) & 127;
        int b = gid >> 14;
        int i = r16 * 16 + (s & 15);
        int e0 = ke * 32 + ((s >> 4) & 3) * 8;
        const float4* src = reinterpret_cast<const float4*>(emb + ((size_t)(b * NN + i)) * EE + e0);
        float4 v0 = src[0], v1 = src[1];
        short8v o;
        o[0] = f2bf(v0.x); o[1] = f2bf(v0.y); o[2] = f2bf(v0.z); o[3] = f2bf(v0.w);
        o[4] = f2bf(v1.x); o[5] = f2bf(v1.y); o[6] = f2bf(v1.z); o[7] = f2bf(v1.w);
        *reinterpret_cast<short8v*>(embq + (size_t)gid * 8) = o;
    } else if (bid < 768) {
        int v = bid - 512;  // b*32 + jt
        int b = v >> 5;
        int jt = v & 31;
        int jb = jt * 64;
#pragma unroll
        for (int k = 0; k < 8; ++k) {
            int idx = t + k * 256;
            int jl = idx >> 5, c4 = idx & 31;
            float4 w = reinterpret_cast<const float4*>(z + ((size_t)(b * NN + jb + jl)) * DD)[c4];
            float* p = &zl[jl * 129 + c4 * 4];
            p[0] = w.x; p[1] = w.y; p[2] = w.z; p[3] = w.w;
        }
        __syncthreads();
#pragma unroll
        for (int k = 0; k < 4; ++k) {
            int sid = t + k * 256;
            int blk = sid >> 6, s = sid & 63;
            int ktl = blk >> 3, nt = blk & 7;
            int d = nt * 16 + (s & 15);
            int jl = ktl * 32 + ((s >> 4) & 3) * 8;
            short8v o;
#pragma unroll
            for (int e = 0; e < 8; ++e) o[e] = f2bf(zl[(jl + e) * 129 + d]);
            *reinterpret_cast<short8v*>(zq + ((size_t)((b * 64 + jt * 2 + ktl) * 8 + nt) * 64 + s) * 8) = o;
        }
    } else {
        int v = bid - 768;
        int q = t & 15;
#pragma unroll
        for (int p = 0; p < 4; ++p) {
            int row = v * 64 + p * 16 + (t >> 4);
            float4 rv = reinterpret_cast<const float4*>(emb + (size_t)row * EE)[q];
            float a0 = __bfloat162float(__float2bfloat16(rv.x));
            float a1 = __bfloat162float(__float2bfloat16(rv.y));
            float a2 = __bfloat162float(__float2bfloat16(rv.z));
            float a3 = __bfloat162float(__float2bfloat16(rv.w));
            float s2 = a0 * a0 + a1 * a1 + a2 * a2 + a3 * a3;
#pragma unroll
            for (int off = 1; off < 16; off <<= 1) s2 += __shfl_xor(s2, off);
            if (q == 0) sq[row] = s2;
        }
    }
}

// ---------------- main MFMA attention, counted-vmcnt pipeline ----------------
// grid: bid = ((js*32 + it))*8 + b (XCD-pinned batch). 4 waves; wave owns 16 rows.
// QK (swapped): lane (g,c) holds S[i=w*16+c][j=J*16+4g+r]. Vote-before-exp skips
// negligible tiles (all p < 1e-6; bounded truncation, out err < ~0.011 worst case).
// Pipeline per tile: compute(buf[cur]) ; s_barrier(A) ; STAGE(buf[cur], jt+2) ;
// vmcnt(3) [retires jt+1's 3 loads, leaves jt+2's in flight] ; s_barrier(B).
// No vmcnt(0) drain in the steady state — prefetch hides under compute.
__global__ __launch_bounds__(256, 4) void attn_mfma(const short* __restrict__ embq,
                                                    const short* __restrict__ zq,
                                                    const float* __restrict__ sq,
                                                    float* __restrict__ outnum,
                                                    float* __restrict__ den,
                                                    int njs) {
    __shared__ short sU[4][1024];      // 8KB union: embI staging (prologue) -> per-wave P^T
    __shared__ int4 sEmbJ[2][512];     // 16KB dbuf [jfr(4)][ke(2)][64]
    __shared__ float sSqJ[2][4][64];   // 2KB dbuf, per-wave copy (uniform 3-op stages)

    const int t = threadIdx.x;
    const int bid = blockIdx.x;
    const int b = bid & 7;
    const int q = bid >> 3;
    const int it = q & 31;
    const int js = q >> 5;
    const int ib = it * 64;
    const int w = t >> 6;
    const int l = t & 63;
    const int g = (l >> 4) & 3;
    const int c = l & 15;

    const int4* embqI4 = (const int4*)embq;
    const short8v* zq8 = (const short8v*)zq;
    const float* sqB = sq + b * NN;

    const int ntiles = 32 / njs;
    const int jt0 = js * ntiles;
    const int jtEnd = jt0 + ntiles;

    int4* sUi = (int4*)&sU[0][0];

    // stage = 3 VMEM ops per thread, uniform across all waves
#define STAGE(buf, tile)                                                       \
    do {                                                                       \
        const int4* _sj = embqI4 + (size_t)(b * 128 + (tile) * 4) * 2 * 64;    \
        GLD16(_sj + t, &sEmbJ[buf][t]);                                        \
        GLD16(_sj + t + 256, &sEmbJ[buf][t + 256]);                            \
        GLD4(sqB + (tile) * 64 + l, &sSqJ[buf][w][0]);                         \
    } while (0)

    // prologue: embI (2 ops) + stage(jt0) + stage(jt0+1); wait embI+tile0 only
    {
        const int4* srcI = embqI4 + (size_t)(b * 128 + it * 4) * 2 * 64;
        GLD16(srcI + t, sUi + t);
        GLD16(srcI + t + 256, sUi + t + 256);
    }
    STAGE(0, jt0);
    STAGE(1, jt0 + 1);
    asm volatile("s_waitcnt vmcnt(3)" ::: "memory");  // embI + tile0 done; tile1 in flight
    __builtin_amdgcn_s_barrier();
    __builtin_amdgcn_sched_barrier(0);

    short8v qkB[2];
    qkB[0] = *reinterpret_cast<const short8v*>(&sUi[(w * 2 + 0) * 64 + l]);
    qkB[1] = *reinterpret_cast<const short8v*>(&sUi[(w * 2 + 1) * 64 + l]);
    const float sqi = sqB[ib + w * 16 + c];

    float dsum = 0.f;
    float4v acc[8];
#pragma unroll
    for (int nt = 0; nt < 8; ++nt) acc[nt] = (float4v){0.f, 0.f, 0.f, 0.f};

    char* ptw = (char*)&sU[w][0];
    const int swz = (c & 7) << 4;

    int cur = 0;
    for (int jt = jt0; jt < jtEnd; ++jt, cur ^= 1) {
        // ---- QK (swapped) + d2 only; no exp yet ----
        float d2v[4][4];
        float d2minJ[4];
#pragma unroll
        for (int J = 0; J < 4; ++J) {
            short8v a0 = *reinterpret_cast<const short8v*>(&sEmbJ[cur][(J * 2 + 0) * 64 + l]);
            short8v a1 = *reinterpret_cast<const short8v*>(&sEmbJ[cur][(J * 2 + 1) * 64 + l]);
            float4v sfr = (float4v){0.f, 0.f, 0.f, 0.f};
            sfr = __builtin_amdgcn_mfma_f32_16x16x32_bf16(a0, qkB[0], sfr, 0, 0, 0);
            sfr = __builtin_amdgcn_mfma_f32_16x16x32_bf16(a1, qkB[1], sfr, 0, 0, 0);
            float4 sqj = *reinterpret_cast<const float4*>(&sSqJ[cur][w][J * 16 + 4 * g]);
            d2v[J][0] = fmaxf(fmaf(-2.0f, sfr[0], sqi + sqj.x), 0.0f);
            d2v[J][1] = fmaxf(fmaf(-2.0f, sfr[1], sqi + sqj.y), 0.0f);
            d2v[J][2] = fmaxf(fmaf(-2.0f, sfr[2], sqi + sqj.z), 0.0f);
            d2v[J][3] = fmaxf(fmaf(-2.0f, sfr[3], sqi + sqj.w), 0.0f);
            d2minJ[J] = fminf(fminf(d2v[J][0], d2v[J][1]), fminf(d2v[J][2], d2v[J][3]));
        }
        float tmin = fminf(fminf(d2minJ[0], d2minJ[1]), fminf(d2minJ[2], d2minJ[3]));

        // ---- exp/pack/PV only when some p >= 1e-6 anywhere in the wave-tile ----
        if (!__all(tmin > 13.8f)) {
#pragma unroll
            for (int J = 0; J < 4; ++J) {
                unsigned long long pword = 0ull;
                if (!__all(d2minJ[J] > 13.8f)) {
                    float p0 = __expf(-d2v[J][0]);
                    float p1 = __expf(-d2v[J][1]);
                    float p2 = __expf(-d2v[J][2]);
                    float p3 = __expf(-d2v[J][3]);
                    dsum += (p0 + p1) + (p2 + p3);
                    pword = (unsigned long long)pack2bf(p0, p1) |
                            ((unsigned long long)pack2bf(p2, p3) << 32);
                }
                *reinterpret_cast<unsigned long long*>(
                    ptw + ((c * 128 + g * 8) ^ swz ^ (J * 32))) = pword;
            }
            short8v pa0 = *reinterpret_cast<const short8v*>(ptw + ((c * 128 + 0 * 64 + g * 16) ^ swz));
            short8v pa1 = *reinterpret_cast<const short8v*>(ptw + ((c * 128 + 1 * 64 + g * 16) ^ swz));
#pragma unroll
            for (int nt = 0; nt < 8; ++nt) {
                short8v z0 = zq8[(size_t)((b * 64 + jt * 2 + 0) * 8 + nt) * 64 + l];
                short8v z1 = zq8[(size_t)((b * 64 + jt * 2 + 1) * 8 + nt) * 64 + l];
                acc[nt] = __builtin_amdgcn_mfma_f32_16x16x32_bf16(pa0, z0, acc[nt], 0, 0, 0);
                acc[nt] = __builtin_amdgcn_mfma_f32_16x16x32_bf16(pa1, z1, acc[nt], 0, 0, 0);
            }
        }

        // ---- pipeline boundary (no full drain) ----
        __builtin_amdgcn_s_barrier();  // (A) all waves done reading buf[cur]
        if (jt + 2 < jtEnd) {
            STAGE(cur, jt + 2);        // overwrite freed buffer; stays in flight
            asm volatile("s_waitcnt vmcnt(3)" ::: "memory");  // retire tile jt+1's stage
        } else {
            asm volatile("s_waitcnt vmcnt(0)" ::: "memory");  // tail: drain remaining
        }
        __builtin_amdgcn_s_barrier();  // (B) next tile visible to all waves
        __builtin_amdgcn_sched_barrier(0);
    }
#undef STAGE

    // dsum reduce over g-groups -> all lanes hold row-c sum
    dsum += __shfl_xor(dsum, 16);
    dsum += __shfl_xor(dsum, 32);

    if (njs == 1) {
        float invr[4];
#pragma unroll
        for (int r = 0; r < 4; ++r) invr[r] = 1.0f / __shfl(dsum, 4 * g + r);
#pragma unroll
        for (int r = 0; r < 4; ++r) {
            size_t row = (size_t)(b * NN + ib + w * 16 + 4 * g + r);
#pragma unroll
            for (int nt = 0; nt < 8; ++nt)
                outnum[row * DD + nt * 16 + c] = acc[nt][r] * invr[r];
        }
    } else {
        if (l < 16) den[(size_t)js * BN + b * NN + ib + w * 16 + l] = dsum;
        if (!__all(dsum < 1e-6f)) {
#pragma unroll
            for (int r = 0; r < 4; ++r) {
                size_t row = (size_t)js * BN + b * NN + ib + w * 16 + 4 * g + r;
#pragma unroll
                for (int nt = 0; nt < 8; ++nt)
                    outnum[row * DD + nt * 16 + c] = acc[nt][r];
            }
        }
    }
}

// ---------------- reduce: out = sum_js num / sum_js den, num reads gated by den ----------------
__global__ __launch_bounds__(256) void reduce_kernel(const float4* __restrict__ num,
                                                     const float* __restrict__ den,
                                                     float4* __restrict__ out,
                                                     int njs) {
    int i4 = blockIdx.x * 256 + threadIdx.x;
    int row = i4 >> 5;
    float4 ns = make_float4(0.f, 0.f, 0.f, 0.f);
    float ds = 0.f;
    for (int js = 0; js < njs; ++js) {
        float dj = den[(size_t)js * BN + row];
        ds += dj;
        if (dj >= 1e-6f) {
            float4 v = num[(size_t)js * ((size_t)BN * (DD / 4)) + i4];
            ns.x += v.x; ns.y += v.y; ns.z += v.z; ns.w += v.w;
        }
    }
    float inv = 1.0f / ds;
    out[i4] = make_float4(ns.x * inv, ns.y * inv, ns.z * inv, ns.w * inv);
}

extern "C" void kernel_launch(void* const* d_in, const int* in_sizes, int n_in,
                              void* d_out, int out_size, void* d_ws, size_t ws_size,
                              hipStream_t stream) {
    (void)in_sizes; (void)n_in; (void)out_size;
    const float* emb = (const float*)d_in[0];
    const float* z = (const float*)d_in[1];
    float* out = (float*)d_out;
    float* ws = (float*)d_ws;

    // ws layout (floats): sq[BN] | den[njs*BN] | num[njs*BN*DD] | embq(1M shorts) | zq(2M shorts)
    int njs = 1;
    if (ws_size >= 40ull * 1024 * 1024) njs = 4;
    else if (ws_size >= 24ull * 1024 * 1024) njs = 2;

    float* sqw = ws;
    float* denw = ws + BN;
    float* numw = denw + (size_t)njs * BN;
    size_t numFloats = (njs > 1) ? (size_t)njs * BN * DD : 0;
    short* embqw = (short*)(numw + numFloats);
    short* zqw = embqw + (size_t)BB * NN * EE;

    prep_kernel<<<1024, 256, 0, stream>>>(emb, z, embqw, zqw, sqw);

    attn_mfma<<<8 * 32 * njs, 256, 0, stream>>>(embqw, zqw, sqw,
                                                njs == 1 ? out : numw, denw, njs);

    if (njs > 1) {
        reduce_kernel<<<(BN * (DD / 4)) / 256, 256, 0, stream>>>(
            (const float4*)numw, denw, (float4*)out, njs);
    }
}